// Round 1
// baseline (540.240 us; speedup 1.0000x reference)
//
#include <hip/hip_runtime.h>
#include <stdint.h>

#define THREADS 512
#define SPB 16                 // samples per block -> 64 A-rows
#define CHUNK_WORDS 4096       // one K=16 W chunk: hi plane 2048 + lo plane 2048 words
#define NCHUNK_TOT 64          // 4 layers x 16 chunks, linearized
#define ALO 8192               // sA lo-plane word offset (hi plane = [0,8192))

typedef __bf16 bf16x8 __attribute__((ext_vector_type(8)));
typedef float f32x16 __attribute__((ext_vector_type(16)));

union Frag { uint32_t u[4]; bf16x8 v; };

__device__ __forceinline__ uint32_t f2bf(float f) {    // RNE bf16 bits
    uint32_t u = __float_as_uint(f);
    return (u + 0x7fffu + ((u >> 16) & 1u)) >> 16;
}
// packed RNE f32x2 -> bf16x2 in ONE VALU op (no builtin on gfx950 -> asm)
__device__ __forceinline__ uint32_t cvtpk_bf16(float a, float b) {
    uint32_t r;
    asm("v_cvt_pk_bf16_f32 %0, %1, %2" : "=v"(r) : "v"(a), "v"(b));
    return r;
}
// hi word = bf16(a)|bf16(b)<<16 ; lo word = residuals. 6 VALU for 2 values.
__device__ __forceinline__ void pack_pair(float a, float b, uint32_t& wh, uint32_t& wl) {
    wh = cvtpk_bf16(a, b);
    float ra = a - __uint_as_float(wh << 16);
    float rb = b - __uint_as_float(wh & 0xffff0000u);
    wl = cvtpk_bf16(ra, rb);
}
__device__ __forceinline__ float wsum(float v) {
    #pragma unroll
    for (int off = 32; off > 0; off >>= 1) v += __shfl_xor(v, off, 64);
    return v;
}
__device__ __forceinline__ float wmax(float v) {
    #pragma unroll
    for (int off = 32; off > 0; off >>= 1) v = fmaxf(v, __shfl_xor(v, off, 64));
    return v;
}

// ---- pre-kernel: pack W into planar hi/lo bf16 k-pair chunk images ----
// word idx = l*65536 + kt*4096 + plane*2048 + s8*1024 + n*4 + w
// PAIR PERMUTATION: pair index kp = kt*8 + s8*4 + w holds logical k's
//   klo(kp) = 2*(kp & ~31) + (kp & 31)   and   khi = klo + 32
// so that in the main kernel a lane's two output columns (n, n+32) form
// one bf16 k-pair IN-LANE (acc[0][r], acc[1][r]) -> cvt_pk, no shuffles.
__global__ __launch_bounds__(256) void pack_w(const float* __restrict__ w_hid,
                                              const float* __restrict__ w_out,
                                              uint32_t* __restrict__ Wp) {
    int idx = blockIdx.x * 256 + threadIdx.x;      // 0..262143
    int l     = idx >> 16;
    int r     = idx & 65535;
    int kt    = r >> 12;
    int r2    = r & 4095;
    int plane = r2 >> 11;
    int r3    = r2 & 2047;
    int s8    = r3 >> 10;
    int n     = (r3 >> 2) & 255;
    int w     = r3 & 3;
    int kp    = kt * 8 + s8 * 4 + w;               // 0..127
    int klo   = 2 * (kp & ~31) + (kp & 31);
    int khi   = klo + 32;
    const float* Wsrc = (l < 3) ? (w_hid + l * 65536) : w_out;
    float a = Wsrc[klo * 256 + n];
    float b = Wsrc[khi * 256 + n];
    uint32_t ha = f2bf(a), hb = f2bf(b);
    uint32_t word;
    if (plane == 0) {
        word = ha | (hb << 16);
    } else {
        uint32_t la = f2bf(a - __uint_as_float(ha << 16));
        uint32_t lb = f2bf(b - __uint_as_float(hb << 16));
        word = la | (lb << 16);
    }
    Wp[idx] = word;
}

// sA planar layout (64 rows): plane + (kq<<8) + ((m ^ (kq&7))<<2) + (kp&3)
// kp = pair index (logical cols klo(kp), klo(kp)+32), kq = kp>>2, m = row 0..63.
// hi plane words [0,8192), lo plane [8192,16384). 64 KB total -> 2 blocks/CU.
//
// Wave tiling: wave w covers rows rh*32..+31 (rh=w>>2) and cols cg*64..+63
// (cg=w&3) as two 32-col tiles acc[0]/acc[1]. Lane ln owns cols n1=cg*64+ln
// and n1+32 -> epilogue bf16 pair is (acc[0][r], acc[1][r]) IN-LANE.
__global__ __launch_bounds__(THREADS, 3) void divfree_mfma(
    const float* __restrict__ x,
    const uint32_t* __restrict__ Wp,
    const float* __restrict__ w_in,
    const float* __restrict__ b_in,
    const float* __restrict__ b_hid,
    const float* __restrict__ b_out,
    float* __restrict__ out)
{
    __shared__ uint32_t lds[16384];                // 64 KB
    const int tid  = threadIdx.x;
    const int wave = tid >> 6, lane = tid & 63;
    const int l5 = lane >> 5, ln = lane & 31;
    const int s0 = blockIdx.x * SPB;
    const int cg = wave & 3;                       // column group (64 cols)
    const int rh = wave >> 2;                      // row half (32 rows)
    const int n1 = cg * 64 + ln;                   // lower output column
    const int n4v = n1 * 4;                        // B-frag word offset (ct=1: +128)

    // 2-deep software-pipelined B prefetch, slots = tt&1, 2 col-tiles each
    uint4 qh[2][2], ql[2][2];
    #pragma unroll
    for (int c = 0; c < 2; ++c) {
        const uint32_t* Bb = Wp + c * CHUNK_WORDS + l5 * 1024;
        qh[c][0] = *(const uint4*)(Bb + n4v);
        ql[c][0] = *(const uint4*)(Bb + 2048 + n4v);
        qh[c][1] = *(const uint4*)(Bb + n4v + 128);
        ql[c][1] = *(const uint4*)(Bb + 2048 + n4v + 128);
    }

    { // ---- input layer: thread owns row m=lane, kq slabs i*8 + wave ----
        const int m   = lane;
        const int s   = m >> 2;
        const int row = m & 3;
        const float x0 = x[(s0 + s) * 3 + 0];
        const float x1 = x[(s0 + s) * 3 + 1];
        const float x2 = x[(s0 + s) * 3 + 2];
        #pragma unroll
        for (int i = 0; i < 4; ++i) {
            const int kq = i * 8 + wave;           // 0..31
            // slab kq = pairs kq*4..kq*4+3 = logical k's {kA..kA+3, kA+32..kA+35}
            const int kA = ((kq >> 3) << 6) + ((kq & 7) << 2);
            float4 w0A = *(const float4*)&w_in[kA];
            float4 w1A = *(const float4*)&w_in[256 + kA];
            float4 w2A = *(const float4*)&w_in[512 + kA];
            float4 bbA = *(const float4*)&b_in[kA];
            float4 w0B = *(const float4*)&w_in[kA + 32];
            float4 w1B = *(const float4*)&w_in[256 + kA + 32];
            float4 w2B = *(const float4*)&w_in[512 + kA + 32];
            float4 bbB = *(const float4*)&b_in[kA + 32];
            float W0A[4] = {w0A.x, w0A.y, w0A.z, w0A.w};
            float W1A[4] = {w1A.x, w1A.y, w1A.z, w1A.w};
            float W2A[4] = {w2A.x, w2A.y, w2A.z, w2A.w};
            float BBA[4] = {bbA.x, bbA.y, bbA.z, bbA.w};
            float W0B[4] = {w0B.x, w0B.y, w0B.z, w0B.w};
            float W1B[4] = {w1B.x, w1B.y, w1B.z, w1B.w};
            float W2B[4] = {w2B.x, w2B.y, w2B.z, w2B.w};
            float BBB[4] = {bbB.x, bbB.y, bbB.z, bbB.w};
            uint32_t hw[4], lw[4];
            #pragma unroll
            for (int e = 0; e < 4; ++e) {
                float preA = x0 * W0A[e] + x1 * W1A[e] + x2 * W2A[e] + BBA[e];
                float sigA = 1.f / (1.f + __expf(-preA));
                float spA  = sigA * (1.f + preA * (1.f - sigA));
                float wsA  = (row == 1) ? W0A[e] : (row == 2) ? W1A[e] : W2A[e];
                float vA   = (row == 0) ? preA * sigA : spA * wsA;
                float preB = x0 * W0B[e] + x1 * W1B[e] + x2 * W2B[e] + BBB[e];
                float sigB = 1.f / (1.f + __expf(-preB));
                float spB  = sigB * (1.f + preB * (1.f - sigB));
                float wsB  = (row == 1) ? W0B[e] : (row == 2) ? W1B[e] : W2B[e];
                float vB   = (row == 0) ? preB * sigB : spB * wsB;
                pack_pair(vA, vB, hw[e], lw[e]);
            }
            const int base = (kq << 8) + ((m ^ (kq & 7)) << 2);
            *(uint4*)&lds[base]       = *(uint4*)hw;
            *(uint4*)&lds[ALO + base] = *(uint4*)lw;
        }
    }
    __syncthreads();

    // A-frag LDS word bases: slot j = tt&3 (kq = 2*tt+l5 -> kq&7 period 4 in tt).
    // Single row-tile per wave (rh) -> 2 ds_read_b128 per tt (was 4).
    int abase[4];
    #pragma unroll
    for (int j = 0; j < 4; ++j) {
        const int kq = 2 * j + l5;
        abase[j] = (kq << 8) + rh * 128 + ((ln ^ (kq & 7)) << 2);
    }

    #pragma unroll 1
    for (int l = 0; l < 4; ++l) {
        f32x16 acc[2];
        acc[0] = (f32x16)0.0f;
        acc[1] = (f32x16)0.0f;

        #pragma unroll
        for (int tt = 0; tt < 16; ++tt) {          // fully unrolled K-loop
            const int slot = tt & 1;
            Frag bh0, bl0, bh1, bl1;
            *(uint4*)&bh0.u[0] = qh[slot][0];
            *(uint4*)&bl0.u[0] = ql[slot][0];
            *(uint4*)&bh1.u[0] = qh[slot][1];
            *(uint4*)&bl1.u[0] = ql[slot][1];
            // refill this slot with chunk lin+2 (uniform -> scalar pipe)
            int lin = l * 16 + tt + 2;
            if (lin > NCHUNK_TOT - 1) lin = NCHUNK_TOT - 1;
            const uint32_t* Bb = Wp + lin * CHUNK_WORDS + l5 * 1024;
            qh[slot][0] = *(const uint4*)(Bb + n4v);
            ql[slot][0] = *(const uint4*)(Bb + 2048 + n4v);
            qh[slot][1] = *(const uint4*)(Bb + n4v + 128);
            ql[slot][1] = *(const uint4*)(Bb + 2048 + n4v + 128);

            // A frags: zero per-step address VALU (base reg + immediate)
            const int aw = abase[tt & 3] + (tt >> 2) * 2048;
            Frag ahi, alo;
            *(uint4*)&ahi.u[0] = *(const uint4*)&lds[aw];
            *(uint4*)&alo.u[0] = *(const uint4*)&lds[ALO + aw];

            acc[0] = __builtin_amdgcn_mfma_f32_32x32x16_bf16(ahi.v, bh0.v, acc[0], 0, 0, 0);
            acc[0] = __builtin_amdgcn_mfma_f32_32x32x16_bf16(alo.v, bh0.v, acc[0], 0, 0, 0);
            acc[0] = __builtin_amdgcn_mfma_f32_32x32x16_bf16(ahi.v, bl0.v, acc[0], 0, 0, 0);
            acc[1] = __builtin_amdgcn_mfma_f32_32x32x16_bf16(ahi.v, bh1.v, acc[1], 0, 0, 0);
            acc[1] = __builtin_amdgcn_mfma_f32_32x32x16_bf16(alo.v, bh1.v, acc[1], 0, 0, 0);
            acc[1] = __builtin_amdgcn_mfma_f32_32x32x16_bf16(ahi.v, bl1.v, acc[1], 0, 0, 0);
        }

        // hoist bias loads above the barrier (no LDS dependence)
        float bn0 = 0.f, bn1 = 0.f;
        if (l < 3) {
            bn0 = b_hid[l * 256 + n1];
            bn1 = b_hid[l * 256 + n1 + 32];
        }
        __syncthreads();                           // all waves done READING sA(l)

        if (l < 3) {
            // C layout per acc: col = n (lane), row = st + 8*rg + 4*l5 (+rh*32)
            // This lane writes pair p = cg*32+ln = cols (n1, n1+32) for 16 rows.
            const int kq    = cg * 8 + (ln >> 2);  // p>>2 ; kq&7 == ln>>2
            const int xr    = ln >> 2;
            const int wbase = (kq << 8) + (ln & 3);
            #pragma unroll
            for (int rg = 0; rg < 4; ++rg) {
                float v0[4], v1[4];
                {
                    const float pre = acc[0][rg * 4 + 0] + bn0;
                    const float sig = 1.f / (1.f + __expf(-pre));
                    const float sp  = sig * (1.f + pre * (1.f - sig));
                    v0[0] = pre * sig;
                    v0[1] = sp * acc[0][rg * 4 + 1];
                    v0[2] = sp * acc[0][rg * 4 + 2];
                    v0[3] = sp * acc[0][rg * 4 + 3];
                }
                {
                    const float pre = acc[1][rg * 4 + 0] + bn1;
                    const float sig = 1.f / (1.f + __expf(-pre));
                    const float sp  = sig * (1.f + pre * (1.f - sig));
                    v1[0] = pre * sig;
                    v1[1] = sp * acc[1][rg * 4 + 1];
                    v1[2] = sp * acc[1][rg * 4 + 2];
                    v1[3] = sp * acc[1][rg * 4 + 3];
                }
                const int mb = rh * 32 + 8 * rg + 4 * l5;
                #pragma unroll
                for (int st = 0; st < 4; ++st) {
                    uint32_t wh, wl;
                    pack_pair(v0[st], v1[st], wh, wl);
                    const int a = wbase + (((mb + st) ^ xr) << 2);
                    lds[a]       = wh;
                    lds[ALO + a] = wl;
                }
            }
            __syncthreads();                       // sA(l+1) visible
        } else {
            // dump raw output-GEMM results to E[smp][state][n] fp32 (overlays sA)
            float* E = (float*)lds;
            #pragma unroll
            for (int ct = 0; ct < 2; ++ct) {
                const int n = n1 + ct * 32;
                #pragma unroll
                for (int rg = 0; rg < 4; ++rg) {
                    const int smp = rh * 8 + 2 * rg + l5;
                    #pragma unroll
                    for (int st = 0; st < 4; ++st)
                        E[(smp * 4 + st) * 256 + n] = acc[ct][rg * 4 + st];
                }
            }
            __syncthreads();
            // final phase: lane = mixture, wave w -> samples 2w..2w+1
            const float4* E4 = (const float4*)lds;
            float4 bo = *(const float4*)&b_out[lane * 4];
            #pragma unroll
            for (int g = 0; g < 2; ++g) {
                const int sl = wave * 2 + g;
                float4 o  = E4[(sl * 4 + 0) * 64 + lane];
                float4 t1 = E4[(sl * 4 + 1) * 64 + lane];
                float4 t2 = E4[(sl * 4 + 2) * 64 + lane];
                float4 t3 = E4[(sl * 4 + 3) * 64 + lane];
                float sm  = o.x + bo.x;
                float oa0 = o.y + bo.y, oa1 = o.z + bo.z, oa2 = o.w + bo.w;
                float ds0 = t1.x, ds1 = t2.x, ds2 = t3.x;
                float mx = wmax(sm);
                float e  = __expf(sm - mx);
                float Z  = wsum(e);
                float T0 = wsum(e * ds0) / Z;
                float T1 = wsum(e * ds1) / Z;
                float T2 = wsum(e * ds2) / Z;
                float g0 =  (ds1 - T1) * oa0 + t2.y + (ds2 - T2) * oa1 + t3.z;
                float g1 = -((ds0 - T0) * oa0 + t1.y) + (ds2 - T2) * oa2 + t3.w;
                float g2 = -((ds0 - T0) * oa1 + t1.z) - ((ds1 - T1) * oa2 + t2.w);
                float u0 = wsum(e * g0) / Z;
                float u1 = wsum(e * g1) / Z;
                float u2 = wsum(e * g2) / Z;
                if (lane == 0) {
                    const int sg = s0 + sl;
                    out[sg * 3 + 0] = u0;
                    out[sg * 3 + 1] = u1;
                    out[sg * 3 + 2] = u2;
                }
            }
        }
    }
}

extern "C" void kernel_launch(void* const* d_in, const int* in_sizes, int n_in,
                              void* d_out, int out_size, void* d_ws, size_t ws_size,
                              hipStream_t stream) {
    const float* x     = (const float*)d_in[0];
    const float* w_in  = (const float*)d_in[1];
    const float* b_in  = (const float*)d_in[2];
    const float* w_hid = (const float*)d_in[3];
    const float* b_hid = (const float*)d_in[4];
    const float* w_out = (const float*)d_in[5];
    const float* b_out = (const float*)d_in[6];
    float* out = (float*)d_out;
    uint32_t* Wp = (uint32_t*)d_ws;                 // 1 MB packed-weight image
    const int N = in_sizes[0] / 3;

    pack_w<<<1024, 256, 0, stream>>>(w_hid, w_out, Wp);
    divfree_mfma<<<N / SPB, THREADS, 0, stream>>>(x, Wp, w_in, b_in, b_hid, b_out, out);
}

// Round 3
// 520.856 us; speedup vs baseline: 1.0372x; 1.0372x over previous
//
#include <hip/hip_runtime.h>
#include <stdint.h>

#define THREADS 256
#define SPB 8                  // samples per block -> 32 A-rows
#define CHUNK_WORDS 4096       // one K=16 W chunk: hi plane 2048 + lo plane 2048 words
#define NCHUNK_TOT 64          // 4 layers x 16 chunks, linearized
#define ALO 4096               // sA lo-plane word offset (hi plane = [0,4096))

typedef __bf16 bf16x8 __attribute__((ext_vector_type(8)));
typedef float f32x16 __attribute__((ext_vector_type(16)));

union Frag { uint32_t u[4]; bf16x8 v; };

__device__ __forceinline__ uint32_t f2bf(float f) {    // RNE bf16 bits
    uint32_t u = __float_as_uint(f);
    return (u + 0x7fffu + ((u >> 16) & 1u)) >> 16;
}
// packed RNE f32x2 -> bf16x2 in ONE VALU op (no builtin on gfx950 -> asm)
__device__ __forceinline__ uint32_t cvtpk_bf16(float a, float b) {
    uint32_t r;
    asm("v_cvt_pk_bf16_f32 %0, %1, %2" : "=v"(r) : "v"(a), "v"(b));
    return r;
}
// hi word = bf16(a)|bf16(b)<<16 ; lo word = residuals. 6 VALU for 2 values.
__device__ __forceinline__ void pack_pair(float a, float b, uint32_t& wh, uint32_t& wl) {
    wh = cvtpk_bf16(a, b);
    float ra = a - __uint_as_float(wh << 16);
    float rb = b - __uint_as_float(wh & 0xffff0000u);
    wl = cvtpk_bf16(ra, rb);
}
__device__ __forceinline__ float wsum(float v) {
    #pragma unroll
    for (int off = 32; off > 0; off >>= 1) v += __shfl_xor(v, off, 64);
    return v;
}
__device__ __forceinline__ float wmax(float v) {
    #pragma unroll
    for (int off = 32; off > 0; off >>= 1) v = fmaxf(v, __shfl_xor(v, off, 64));
    return v;
}

// ---- pre-kernel: pack W into planar hi/lo bf16 k-pair chunk images ----
// word idx = l*65536 + kt*4096 + plane*2048 + s8*1024 + n*4 + w
// PAIR PERMUTATION: pair index kp = kt*8 + s8*4 + w holds logical k's
//   klo(kp) = 2*(kp & ~31) + (kp & 31)   and   khi = klo + 32
// so that in the main kernel a lane's two output columns (n, n+32) form
// one bf16 k-pair IN-LANE (acc[0][r], acc[1][r]) -> cvt_pk, no shuffles.
__global__ __launch_bounds__(256) void pack_w(const float* __restrict__ w_hid,
                                              const float* __restrict__ w_out,
                                              uint32_t* __restrict__ Wp) {
    int idx = blockIdx.x * 256 + threadIdx.x;      // 0..262143
    int l     = idx >> 16;
    int r     = idx & 65535;
    int kt    = r >> 12;
    int r2    = r & 4095;
    int plane = r2 >> 11;
    int r3    = r2 & 2047;
    int s8    = r3 >> 10;
    int n     = (r3 >> 2) & 255;
    int w     = r3 & 3;
    int kp    = kt * 8 + s8 * 4 + w;               // 0..127
    int klo   = 2 * (kp & ~31) + (kp & 31);
    int khi   = klo + 32;
    const float* Wsrc = (l < 3) ? (w_hid + l * 65536) : w_out;
    float a = Wsrc[klo * 256 + n];
    float b = Wsrc[khi * 256 + n];
    uint32_t ha = f2bf(a), hb = f2bf(b);
    uint32_t word;
    if (plane == 0) {
        word = ha | (hb << 16);
    } else {
        uint32_t la = f2bf(a - __uint_as_float(ha << 16));
        uint32_t lb = f2bf(b - __uint_as_float(hb << 16));
        word = la | (lb << 16);
    }
    Wp[idx] = word;
}

// sA planar layout (32 rows): plane + (kq<<7) + ((m ^ (kq&7))<<2) + (kp&3)
// kp = pair index (logical cols klo(kp), klo(kp)+32), kq = kp>>2, m = row 0..31.
// hi plane words [0,4096), lo plane [4096,8192). 32 KB total -> up to 5 blocks/CU.
//
// Wave tiling: 4 waves, wave w = column group cg (64 cols, two 32-col tiles
// acc[0]/acc[1]); every wave covers ALL 32 rows. Column sets are DISJOINT
// across waves -> each B word read once per block (no rh duplication).
// Lane ln owns cols n1=cg*64+ln and n1+32 -> bf16 pair IN-LANE.
// 4-wave blocks @32KB LDS -> 4-5 independent barrier domains per CU: one
// block's barrier/L2-latency stalls are hidden by the other blocks' MFMAs.
__global__ __launch_bounds__(THREADS, 4) void divfree_mfma(
    const float* __restrict__ x,
    const uint32_t* __restrict__ Wp,
    const float* __restrict__ w_in,
    const float* __restrict__ b_in,
    const float* __restrict__ b_hid,
    const float* __restrict__ b_out,
    float* __restrict__ out)
{
    __shared__ uint32_t lds[8192];                 // 32 KB
    const int tid  = threadIdx.x;
    const int wave = tid >> 6, lane = tid & 63;
    const int l5 = lane >> 5, ln = lane & 31;
    const int s0 = blockIdx.x * SPB;
    const int cg = wave;                           // column group (64 cols)
    const int n1 = cg * 64 + ln;                   // lower output column
    const int n4v = n1 * 4;                        // B-frag word offset (ct=1: +128)

    // 2-deep software-pipelined B prefetch, slots = tt&1, 2 col-tiles each
    uint4 qh[2][2], ql[2][2];
    #pragma unroll
    for (int c = 0; c < 2; ++c) {
        const uint32_t* Bb = Wp + c * CHUNK_WORDS + l5 * 1024;
        qh[c][0] = *(const uint4*)(Bb + n4v);
        ql[c][0] = *(const uint4*)(Bb + 2048 + n4v);
        qh[c][1] = *(const uint4*)(Bb + n4v + 128);
        ql[c][1] = *(const uint4*)(Bb + 2048 + n4v + 128);
    }

    { // ---- input layer: thread owns row m=tid&31, kq slabs i*8 + (tid>>5) ----
        const int m   = tid & 31;
        const int g   = tid >> 5;                  // 0..7
        const int s   = m >> 2;
        const int row = m & 3;
        const float x0 = x[(s0 + s) * 3 + 0];
        const float x1 = x[(s0 + s) * 3 + 1];
        const float x2 = x[(s0 + s) * 3 + 2];
        #pragma unroll
        for (int i = 0; i < 4; ++i) {
            const int kq = i * 8 + g;              // 0..31
            // slab kq = pairs kq*4..kq*4+3 = logical k's {kA..kA+3, kA+32..kA+35}
            const int kA = ((kq >> 3) << 6) + ((kq & 7) << 2);
            float4 w0A = *(const float4*)&w_in[kA];
            float4 w1A = *(const float4*)&w_in[256 + kA];
            float4 w2A = *(const float4*)&w_in[512 + kA];
            float4 bbA = *(const float4*)&b_in[kA];
            float4 w0B = *(const float4*)&w_in[kA + 32];
            float4 w1B = *(const float4*)&w_in[256 + kA + 32];
            float4 w2B = *(const float4*)&w_in[512 + kA + 32];
            float4 bbB = *(const float4*)&b_in[kA + 32];
            float W0A[4] = {w0A.x, w0A.y, w0A.z, w0A.w};
            float W1A[4] = {w1A.x, w1A.y, w1A.z, w1A.w};
            float W2A[4] = {w2A.x, w2A.y, w2A.z, w2A.w};
            float BBA[4] = {bbA.x, bbA.y, bbA.z, bbA.w};
            float W0B[4] = {w0B.x, w0B.y, w0B.z, w0B.w};
            float W1B[4] = {w1B.x, w1B.y, w1B.z, w1B.w};
            float W2B[4] = {w2B.x, w2B.y, w2B.z, w2B.w};
            float BBB[4] = {bbB.x, bbB.y, bbB.z, bbB.w};
            uint32_t hw[4], lw[4];
            #pragma unroll
            for (int e = 0; e < 4; ++e) {
                float preA = x0 * W0A[e] + x1 * W1A[e] + x2 * W2A[e] + BBA[e];
                float sigA = 1.f / (1.f + __expf(-preA));
                float spA  = sigA * (1.f + preA * (1.f - sigA));
                float wsA  = (row == 1) ? W0A[e] : (row == 2) ? W1A[e] : W2A[e];
                float vA   = (row == 0) ? preA * sigA : spA * wsA;
                float preB = x0 * W0B[e] + x1 * W1B[e] + x2 * W2B[e] + BBB[e];
                float sigB = 1.f / (1.f + __expf(-preB));
                float spB  = sigB * (1.f + preB * (1.f - sigB));
                float wsB  = (row == 1) ? W0B[e] : (row == 2) ? W1B[e] : W2B[e];
                float vB   = (row == 0) ? preB * sigB : spB * wsB;
                pack_pair(vA, vB, hw[e], lw[e]);
            }
            const int base = (kq << 7) + ((m ^ (kq & 7)) << 2);
            *(uint4*)&lds[base]       = *(uint4*)hw;
            *(uint4*)&lds[ALO + base] = *(uint4*)lw;
        }
    }
    __syncthreads();

    // A-frag LDS word bases: slot j = tt&3 (kq = 2*tt+l5 -> kq&7 period 4 in tt).
    // 32-row sA: low/high half-waves read adjacent 512B slabs -> 1KB/instr, free.
    int abase[4];
    #pragma unroll
    for (int j = 0; j < 4; ++j) {
        const int kq = 2 * j + l5;
        abase[j] = (kq << 7) + ((ln ^ (kq & 7)) << 2);
    }

    #pragma unroll 1
    for (int l = 0; l < 4; ++l) {
        f32x16 acc[2];
        acc[0] = (f32x16)0.0f;
        acc[1] = (f32x16)0.0f;

        #pragma unroll
        for (int tt = 0; tt < 16; ++tt) {          // fully unrolled K-loop
            const int slot = tt & 1;
            Frag bh0, bl0, bh1, bl1;
            *(uint4*)&bh0.u[0] = qh[slot][0];
            *(uint4*)&bl0.u[0] = ql[slot][0];
            *(uint4*)&bh1.u[0] = qh[slot][1];
            *(uint4*)&bl1.u[0] = ql[slot][1];
            // refill this slot with chunk lin+2 (uniform -> scalar pipe)
            int lin = l * 16 + tt + 2;
            if (lin > NCHUNK_TOT - 1) lin = NCHUNK_TOT - 1;
            const uint32_t* Bb = Wp + lin * CHUNK_WORDS + l5 * 1024;
            qh[slot][0] = *(const uint4*)(Bb + n4v);
            ql[slot][0] = *(const uint4*)(Bb + 2048 + n4v);
            qh[slot][1] = *(const uint4*)(Bb + n4v + 128);
            ql[slot][1] = *(const uint4*)(Bb + 2048 + n4v + 128);

            // A frags: zero per-step address VALU (base reg + immediate)
            const int aw = abase[tt & 3] + (tt >> 2) * 1024;
            Frag ahi, alo;
            *(uint4*)&ahi.u[0] = *(const uint4*)&lds[aw];
            *(uint4*)&alo.u[0] = *(const uint4*)&lds[ALO + aw];

            __builtin_amdgcn_s_setprio(1);
            acc[0] = __builtin_amdgcn_mfma_f32_32x32x16_bf16(ahi.v, bh0.v, acc[0], 0, 0, 0);
            acc[0] = __builtin_amdgcn_mfma_f32_32x32x16_bf16(alo.v, bh0.v, acc[0], 0, 0, 0);
            acc[0] = __builtin_amdgcn_mfma_f32_32x32x16_bf16(ahi.v, bl0.v, acc[0], 0, 0, 0);
            acc[1] = __builtin_amdgcn_mfma_f32_32x32x16_bf16(ahi.v, bh1.v, acc[1], 0, 0, 0);
            acc[1] = __builtin_amdgcn_mfma_f32_32x32x16_bf16(alo.v, bh1.v, acc[1], 0, 0, 0);
            acc[1] = __builtin_amdgcn_mfma_f32_32x32x16_bf16(ahi.v, bl1.v, acc[1], 0, 0, 0);
            __builtin_amdgcn_s_setprio(0);
        }

        // hoist bias loads above the barrier (no LDS dependence)
        float bn0 = 0.f, bn1 = 0.f;
        if (l < 3) {
            bn0 = b_hid[l * 256 + n1];
            bn1 = b_hid[l * 256 + n1 + 32];
        }
        __syncthreads();                           // all waves done READING sA(l)

        if (l < 3) {
            // C layout per acc: col = n (lane ln), row = st + 8*rg + 4*l5
            // This lane writes pair p = cg*32+ln = cols (n1, n1+32) for 16 rows.
            const int kq    = cg * 8 + (ln >> 2);  // p>>2 ; kq&7 == ln>>2
            const int xr    = ln >> 2;
            const int wbase = (kq << 7) + (ln & 3);
            #pragma unroll
            for (int rg = 0; rg < 4; ++rg) {
                float v0[4], v1[4];
                {
                    const float pre = acc[0][rg * 4 + 0] + bn0;
                    const float sig = 1.f / (1.f + __expf(-pre));
                    const float sp  = sig * (1.f + pre * (1.f - sig));
                    v0[0] = pre * sig;
                    v0[1] = sp * acc[0][rg * 4 + 1];
                    v0[2] = sp * acc[0][rg * 4 + 2];
                    v0[3] = sp * acc[0][rg * 4 + 3];
                }
                {
                    const float pre = acc[1][rg * 4 + 0] + bn1;
                    const float sig = 1.f / (1.f + __expf(-pre));
                    const float sp  = sig * (1.f + pre * (1.f - sig));
                    v1[0] = pre * sig;
                    v1[1] = sp * acc[1][rg * 4 + 1];
                    v1[2] = sp * acc[1][rg * 4 + 2];
                    v1[3] = sp * acc[1][rg * 4 + 3];
                }
                const int mb = 8 * rg + 4 * l5;
                #pragma unroll
                for (int st = 0; st < 4; ++st) {
                    uint32_t wh, wl;
                    pack_pair(v0[st], v1[st], wh, wl);
                    const int a = wbase + (((mb + st) ^ xr) << 2);
                    lds[a]       = wh;
                    lds[ALO + a] = wl;
                }
            }
            __syncthreads();                       // sA(l+1) visible
        } else {
            // dump raw output-GEMM results to E[smp][state][n] fp32 (overlays sA)
            float* E = (float*)lds;
            #pragma unroll
            for (int ct = 0; ct < 2; ++ct) {
                const int n = n1 + ct * 32;
                #pragma unroll
                for (int rg = 0; rg < 4; ++rg) {
                    const int smp = 2 * rg + l5;
                    #pragma unroll
                    for (int st = 0; st < 4; ++st)
                        E[(smp * 4 + st) * 256 + n] = acc[ct][rg * 4 + st];
                }
            }
            __syncthreads();
            // final phase: lane = mixture, wave w -> samples 2w..2w+1
            const float4* E4 = (const float4*)lds;
            float4 bo = *(const float4*)&b_out[lane * 4];
            #pragma unroll
            for (int g = 0; g < 2; ++g) {
                const int sl = wave * 2 + g;       // 0..7
                float4 o  = E4[(sl * 4 + 0) * 64 + lane];
                float4 t1 = E4[(sl * 4 + 1) * 64 + lane];
                float4 t2 = E4[(sl * 4 + 2) * 64 + lane];
                float4 t3 = E4[(sl * 4 + 3) * 64 + lane];
                float sm  = o.x + bo.x;
                float oa0 = o.y + bo.y, oa1 = o.z + bo.z, oa2 = o.w + bo.w;
                float ds0 = t1.x, ds1 = t2.x, ds2 = t3.x;
                float mx = wmax(sm);
                float e  = __expf(sm - mx);
                float Z  = wsum(e);
                float T0 = wsum(e * ds0) / Z;
                float T1 = wsum(e * ds1) / Z;
                float T2 = wsum(e * ds2) / Z;
                float g0 =  (ds1 - T1) * oa0 + t2.y + (ds2 - T2) * oa1 + t3.z;
                float g1 = -((ds0 - T0) * oa0 + t1.y) + (ds2 - T2) * oa2 + t3.w;
                float g2 = -((ds0 - T0) * oa1 + t1.z) - ((ds1 - T1) * oa2 + t2.w);
                float u0 = wsum(e * g0) / Z;
                float u1 = wsum(e * g1) / Z;
                float u2 = wsum(e * g2) / Z;
                if (lane == 0) {
                    const int sg = s0 + sl;
                    out[sg * 3 + 0] = u0;
                    out[sg * 3 + 1] = u1;
                    out[sg * 3 + 2] = u2;
                }
            }
        }
    }
}

extern "C" void kernel_launch(void* const* d_in, const int* in_sizes, int n_in,
                              void* d_out, int out_size, void* d_ws, size_t ws_size,
                              hipStream_t stream) {
    const float* x     = (const float*)d_in[0];
    const float* w_in  = (const float*)d_in[1];
    const float* b_in  = (const float*)d_in[2];
    const float* w_hid = (const float*)d_in[3];
    const float* b_hid = (const float*)d_in[4];
    const float* w_out = (const float*)d_in[5];
    const float* b_out = (const float*)d_in[6];
    float* out = (float*)d_out;
    uint32_t* Wp = (uint32_t*)d_ws;                 // 1 MB packed-weight image
    const int N = in_sizes[0] / 3;

    pack_w<<<1024, 256, 0, stream>>>(w_hid, w_out, Wp);
    divfree_mfma<<<N / SPB, THREADS, 0, stream>>>(x, Wp, w_in, b_in, b_hid, b_out, out);
}